// Round 12
// baseline (271.147 us; speedup 1.0000x reference)
//
#include <hip/hip_runtime.h>
#include <hip/hip_bf16.h>
#include <stdint.h>

// EncoderBlock: x(4,1024,768) -> MHA(12 heads, D=64) -> +res, LN -> FFN(3072,ReLU) -> +res, LN
// Output FP32. Internal compute bf16 MFMA with fp32 accumulation.

typedef __bf16 bf16;
typedef __attribute__((ext_vector_type(4))) __bf16 bf16x4;
typedef __attribute__((ext_vector_type(8))) __bf16 bf16x8;
typedef __attribute__((ext_vector_type(4))) float f32x4;

#define TOK 4096
#define MDIM 768
#define HH 12
#define FFD 3072

static __device__ __forceinline__ void gload_lds16(const bf16* g, bf16* l) {
  __builtin_amdgcn_global_load_lds(
      (const __attribute__((address_space(1))) unsigned int*)g,
      (__attribute__((address_space(3))) unsigned int*)l, 16, 0, 0);
}

static __device__ __forceinline__ f32x4 mfma16(bf16x8 a, bf16x8 b, f32x4 c) {
  return __builtin_amdgcn_mfma_f32_16x16x32_bf16(a, b, c, 0, 0, 0);
}

// ---------------- prep kernels ----------------

__global__ __launch_bounds__(256) void k_cast_x(const float4* __restrict__ x,
                                                bf16x4* __restrict__ xb, int n4) {
  int i = blockIdx.x * 256 + threadIdx.x;
  if (i >= n4) return;
  float4 v = x[i];
  bf16x4 o = {(bf16)v.x, (bf16)v.y, (bf16)v.z, (bf16)v.w};
  xb[i] = o;
}

// Wq/Wk/Wv (H,M,D) f32 -> Wqkv_t (2304 out-ch, 768 in) bf16, row o = s*768 + h*64 + d
// Wq scaled by 1/8 (folds the 1/sqrt(D) softmax scale into Q).
__global__ __launch_bounds__(256) void k_build_wqkv(const float* __restrict__ Wq,
                                                    const float* __restrict__ Wk,
                                                    const float* __restrict__ Wv,
                                                    bf16* __restrict__ dst) {
  int mt = blockIdx.x, h = blockIdx.y, s = blockIdx.z;
  const float* src = (s == 0 ? Wq : s == 1 ? Wk : Wv) + (size_t)h * 768 * 64;
  float scale = (s == 0) ? 0.125f : 1.0f;
  __shared__ bf16 t[64][65];
  int tid = threadIdx.x;
#pragma unroll
  for (int rep = 0; rep < 16; rep++) {
    int lin = rep * 256 + tid;
    int m = lin >> 6, d = lin & 63;
    t[m][d] = (bf16)(src[(size_t)(mt * 64 + m) * 64 + d] * scale);
  }
  __syncthreads();
#pragma unroll
  for (int rep = 0; rep < 16; rep++) {
    int lin = rep * 256 + tid;
    int d = lin >> 6, m = lin & 63;
    dst[(size_t)(s * 768 + h * 64 + d) * 768 + mt * 64 + m] = t[m][d];
  }
}

// generic (R,C) f32 -> (C,R) bf16 transpose, 64x64 tiles; grid = (C/64, R/64)
__global__ __launch_bounds__(256) void k_transpose(const float* __restrict__ src,
                                                   bf16* __restrict__ dst, int R, int C) {
  __shared__ bf16 t[64][65];
  int ct = blockIdx.x * 64, rt = blockIdx.y * 64;
  int tid = threadIdx.x;
#pragma unroll
  for (int rep = 0; rep < 16; rep++) {
    int lin = rep * 256 + tid;
    int r = lin >> 6, c = lin & 63;
    t[r][c] = (bf16)src[(size_t)(rt + r) * C + ct + c];
  }
  __syncthreads();
#pragma unroll
  for (int rep = 0; rep < 16; rep++) {
    int lin = rep * 256 + tid;
    int c = lin >> 6, r = lin & 63;
    dst[(size_t)(ct + c) * R + rt + r] = t[r][c];
  }
}

__global__ __launch_bounds__(256) void k_bias_qkv(const float* __restrict__ bq,
                                                  const float* __restrict__ bk,
                                                  const float* __restrict__ bv,
                                                  float* __restrict__ dst) {
  int i = blockIdx.x * 256 + threadIdx.x;
  if (i < 768) dst[i] = bq[i] * 0.125f;
  else if (i < 1536) dst[i] = bk[i - 768];
  else if (i < 2304) dst[i] = bv[i - 1536];
}

// ---------------- GEMM (128x64 tile, BK=64, single-buffer, T2-swizzled, T1 XCD-swizzle)
// A (Mr,K) bf16 row-major; Bt (Nc,K) bf16 row-major (= B transposed).
// 128x64 tiles double the block count vs 128x128 -> 4.5-6 blocks/CU, so cross-block
// wave overlap (m114) hides the 2-barrier stage drain (proven by k_gemm_sk's rate).
// EPI 0: QKV: Q/K -> [h][n][tok][d] bf16 (+bias); V -> transposed [h][n][d][tok] (+bias)
// EPI 2: outb bf16 = relu(acc + bias[col])
template <int EPI>
__global__ __launch_bounds__(256) void k_gemm(const bf16* __restrict__ A,
                                              const bf16* __restrict__ Bt,
                                              const float* __restrict__ bias,
                                              const float* __restrict__ res,
                                              float* __restrict__ outf,
                                              bf16* __restrict__ outb,
                                              bf16* __restrict__ q, bf16* __restrict__ kk,
                                              bf16* __restrict__ v,
                                              int Mr, int Nc, int K) {
  __shared__ bf16 As[128 * 64];
  __shared__ bf16 Bs[64 * 64];
  int tid = threadIdx.x, wave = tid >> 6, lane = tid & 63;
  int q_ = lane & 15, hi = lane >> 4;
  // T1: XCD-aware remap (grid size divisible by 8)
  int gx = gridDim.x;
  int bid = blockIdx.y * gx + blockIdx.x;
  int nwg = gx * gridDim.y;
  int logical = (bid & 7) * (nwg >> 3) + (bid >> 3);
  int bx = logical % gx, by = logical / gx;
  int rb = by * 128, cb = bx * 64;
  int wr = (wave >> 1) * 64, wc = (wave & 1) * 32;
  int srow = lane >> 3, jsw = (lane & 7) ^ srow;  // pre-swizzled source slot

  f32x4 acc[4][2];
#pragma unroll
  for (int m = 0; m < 4; m++)
#pragma unroll
    for (int n = 0; n < 2; n++) acc[m][n] = f32x4{0.f, 0.f, 0.f, 0.f};

  for (int k0 = 0; k0 < K; k0 += 64) {
#pragma unroll
    for (int j = 0; j < 4; j++) {
      int row = wave * 32 + j * 8;
      const bf16* ga = A + (size_t)(rb + row + srow) * K + k0 + jsw * 8;
      gload_lds16(ga, &As[row * 64]);
    }
#pragma unroll
    for (int j = 0; j < 2; j++) {
      int row = wave * 16 + j * 8;
      const bf16* gb = Bt + (size_t)(cb + row + srow) * K + k0 + jsw * 8;
      gload_lds16(gb, &Bs[row * 64]);
    }
    __syncthreads();
#pragma unroll
    for (int ks = 0; ks < 2; ks++) {
      bf16x8 af[4], bfr[2];
#pragma unroll
      for (int m = 0; m < 4; m++) {
        int r_ = wr + m * 16 + q_;
        af[m] = *(const bf16x8*)((const char*)&As[r_ * 64] +
                                 ((ks * 64 + hi * 16) ^ ((r_ & 7) << 4)));
      }
#pragma unroll
      for (int n = 0; n < 2; n++) {
        int r_ = wc + n * 16 + q_;
        bfr[n] = *(const bf16x8*)((const char*)&Bs[r_ * 64] +
                                  ((ks * 64 + hi * 16) ^ ((r_ & 7) << 4)));
      }
#pragma unroll
      for (int m = 0; m < 4; m++)
#pragma unroll
        for (int n = 0; n < 2; n++) acc[m][n] = mfma16(af[m], bfr[n], acc[m][n]);
    }
    __syncthreads();
  }

#pragma unroll
  for (int m = 0; m < 4; m++) {
#pragma unroll
    for (int n = 0; n < 2; n++) {
      int col = cb + wc + n * 16 + q_;
      if (EPI == 0) {
        int sec = col / 768;
        int cm = col - sec * 768;
        int h = cm >> 6, d = cm & 63;
        float b = bias[col];
        if (sec < 2) {
          bf16* dst = (sec == 0 ? q : kk);
#pragma unroll
          for (int r = 0; r < 4; r++) {
            int row = rb + wr + m * 16 + hi * 4 + r;
            float val = acc[m][n][r] + b;
            dst[(((size_t)(h * 4 + (row >> 10))) * 1024 + (row & 1023)) * 64 + d] = (bf16)val;
          }
        } else {
          // V transposed: [h*4+nb][d][token], 4 consecutive tokens -> 8B packed store
          int t0 = rb + wr + m * 16 + hi * 4;
          int nb2 = t0 >> 10, tk = t0 & 1023;
          bf16x4 pk;
#pragma unroll
          for (int r = 0; r < 4; r++) pk[r] = (bf16)(acc[m][n][r] + b);
          *(bf16x4*)&v[(((size_t)(h * 4 + nb2)) * 64 + d) * 1024 + tk] = pk;
        }
      } else {
#pragma unroll
        for (int r = 0; r < 4; r++) {
          int row = rb + wr + m * 16 + hi * 4 + r;
          float t = acc[m][n][r] + bias[col];
          outb[(size_t)row * Nc + col] = (bf16)fmaxf(t, 0.f);
        }
      }
    }
  }
}

// ---------------- split-K GEMM (BM=128, BN=64, BK=64, 2 K-slices, swizzled, T1) --------
// For the N=768 GEMMs (out-proj, FF2). Grid (Nc/64, Mr/128, 2) = 768 blocks = 3/CU.
// Writes raw fp32 partials (reduced in LN).
__global__ __launch_bounds__(256) void k_gemm_sk(const bf16* __restrict__ A,
                                                 const bf16* __restrict__ Bt,
                                                 float* __restrict__ part,
                                                 int Nc, int K) {
  __shared__ bf16 As[128 * 64];
  __shared__ bf16 Bs[64 * 64];
  int tid = threadIdx.x, wave = tid >> 6, lane = tid & 63;
  int q = lane & 15, hi = lane >> 4;
  // T1: XCD-aware remap over the flattened 3-D grid (bx fastest)
  int gx = gridDim.x, gy = gridDim.y;
  int flat = (blockIdx.z * gy + blockIdx.y) * gx + blockIdx.x;
  int nwg = gx * gy * gridDim.z;
  int logical = (flat & 7) * (nwg >> 3) + (flat >> 3);
  int bx = logical % gx;
  int tmp = logical / gx;
  int by = tmp % gy, kz = tmp / gy;
  int rb = by * 128, cb = bx * 64;
  int wr = (wave >> 1) * 64, wc = (wave & 1) * 32;
  int ksz = K >> 1;
  int srow = lane >> 3, jsw = (lane & 7) ^ srow;  // pre-swizzled source slot (rule #21)

  f32x4 acc[4][2];
#pragma unroll
  for (int m = 0; m < 4; m++)
#pragma unroll
    for (int n = 0; n < 2; n++) acc[m][n] = f32x4{0.f, 0.f, 0.f, 0.f};

  for (int k0 = kz * ksz; k0 < kz * ksz + ksz; k0 += 64) {
#pragma unroll
    for (int j = 0; j < 4; j++) {
      int row = wave * 32 + j * 8;
      const bf16* ga = A + (size_t)(rb + row + srow) * K + k0 + jsw * 8;
      gload_lds16(ga, &As[row * 64]);
    }
#pragma unroll
    for (int j = 0; j < 2; j++) {
      int row = wave * 16 + j * 8;
      const bf16* gb = Bt + (size_t)(cb + row + srow) * K + k0 + jsw * 8;
      gload_lds16(gb, &Bs[row * 64]);
    }
    __syncthreads();
#pragma unroll
    for (int ks = 0; ks < 2; ks++) {
      bf16x8 af[4], bfr[2];
#pragma unroll
      for (int m = 0; m < 4; m++) {
        int r_ = wr + m * 16 + q;
        af[m] = *(const bf16x8*)((const char*)&As[r_ * 64] +
                                 ((ks * 64 + hi * 16) ^ ((r_ & 7) << 4)));
      }
#pragma unroll
      for (int n = 0; n < 2; n++) {
        int r_ = wc + n * 16 + q;
        bfr[n] = *(const bf16x8*)((const char*)&Bs[r_ * 64] +
                                  ((ks * 64 + hi * 16) ^ ((r_ & 7) << 4)));
      }
#pragma unroll
      for (int m = 0; m < 4; m++)
#pragma unroll
        for (int n = 0; n < 2; n++) acc[m][n] = mfma16(af[m], bfr[n], acc[m][n]);
    }
    __syncthreads();
  }

  float* dst = part + (size_t)kz * TOK * Nc;
#pragma unroll
  for (int m = 0; m < 4; m++)
#pragma unroll
    for (int n = 0; n < 2; n++) {
      int col = cb + wc + n * 16 + q;
#pragma unroll
      for (int r = 0; r < 4; r++) {
        int row = rb + wr + m * 16 + hi * 4 + r;
        dst[(size_t)row * Nc + col] = acc[m][n][r];
      }
    }
}

// ---------------- fused flash attention (LDS-DMA double-buffered, swapped QK^T) ----------------
// 1-D grid of 768 blocks, XCD-decoded so all 16 q-tiles of one (h,n) share an XCD.
// Q,K: [h*4+nb][1024][64] bf16 (Q pre-scaled by 1/8). Vt: [h*4+nb][64][1024] bf16.
// Y out: [nb*1024+tok][h*64+d] bf16.
__global__ __launch_bounds__(256) void k_attn(const bf16* __restrict__ Q,
                                              const bf16* __restrict__ Kb,
                                              const bf16* __restrict__ Vt,
                                              bf16* __restrict__ Y) {
  __shared__ bf16 Ks[2][64 * 64];
  __shared__ bf16 Vs[2][64 * 64];
  __shared__ bf16 Pl[4][1024];  // per-wave 16x64 P^T tile, XOR-swizzled rows (2KB/wave)
  int L = blockIdx.x;
  int grp = L >> 3;
  int pair = ((grp >> 4) << 3) | (L & 7);  // h*4+nb; same-pair blocks share XCD
  int qt = grp & 15;
  int h = pair >> 2, nb = pair & 3;
  int tid = threadIdx.x, w = tid >> 6, lane = tid & 63;
  int q = lane & 15, hi = lane >> 4;
  size_t hn = (size_t)pair * 1024;

  int srow = lane >> 3;
  int jsw = (lane & 7) ^ srow;
  const bf16* kg0 = Kb + hn * 64;
  const bf16* vg0 = Vt + (size_t)pair * 64 * 1024;

  auto stage = [&](int kt, int buf) {
#pragma unroll
    for (int c2 = 0; c2 < 2; c2++) {
      int c = w * 2 + c2;  // chunk 0..7 (8 rows each)
      const bf16* gk = kg0 + (size_t)(kt * 64 + c * 8 + srow) * 64 + jsw * 8;
      gload_lds16(gk, &Ks[buf][c * 8 * 64]);
      const bf16* gv = vg0 + (size_t)(c * 8 + srow) * 1024 + kt * 64 + jsw * 8;
      gload_lds16(gv, &Vs[buf][c * 8 * 64]);
    }
  };

  stage(0, 0);

  const bf16* qptr = Q + (hn + qt * 64 + w * 16 + q) * 64 + hi * 8;
  bf16x8 qf0 = *(const bf16x8*)qptr;
  bf16x8 qf1 = *(const bf16x8*)(qptr + 32);

  float m = -1e30f, l = 0.f;
  f32x4 oacc[4];
#pragma unroll
  for (int dt = 0; dt < 4; dt++) oacc[dt] = f32x4{0.f, 0.f, 0.f, 0.f};
  char* Pw = (char*)&Pl[w][0];
  int sw = (q & 7) << 4;  // read-side row XOR (bytes)

  __syncthreads();  // drains stage(0) DMA + Q loads

  int cur = 0;
#pragma unroll 1
  for (int kt = 0; kt < 16; kt++) {
    if (kt < 15) stage(kt + 1, cur ^ 1);  // DMA for next tile, overlaps this iter
    f32x4 sa[4];
#pragma unroll
    for (int ct = 0; ct < 4; ct++) {
      const char* kb_ = (const char*)&Ks[cur][(ct * 16 + q) * 64];
      bf16x8 kf0 = *(const bf16x8*)(kb_ + ((hi * 16) ^ sw));
      bf16x8 kf1 = *(const bf16x8*)(kb_ + ((64 + hi * 16) ^ sw));
      f32x4 z = {0.f, 0.f, 0.f, 0.f};
      z = mfma16(kf0, qf0, z);
      sa[ct] = mfma16(kf1, qf1, z);
    }
    float mx = sa[0][0];
#pragma unroll
    for (int ct = 0; ct < 4; ct++)
#pragma unroll
      for (int r = 0; r < 4; r++) mx = fmaxf(mx, sa[ct][r]);
    mx = fmaxf(mx, __shfl_xor(mx, 16, 64));
    mx = fmaxf(mx, __shfl_xor(mx, 32, 64));
    if (!__all(mx <= m)) {
      float mn = fmaxf(m, mx);
      float alpha = __expf(m - mn);
      m = mn;
      l *= alpha;
#pragma unroll
      for (int r = 0; r < 4; r++) {
        float ar = __shfl(alpha, hi * 4 + r, 64);
#pragma unroll
        for (int dt = 0; dt < 4; dt++) oacc[dt][r] *= ar;
      }
    }
    float rs = 0.f;
#pragma unroll
    for (int ct = 0; ct < 4; ct++) {
      bf16x4 p4;
#pragma unroll
      for (int r = 0; r < 4; r++) {
        float p = __expf(sa[ct][r] - m);
        rs += p;
        p4[r] = (bf16)p;
      }
      int wbyte = (q * 128 + ct * 32 + hi * 8) ^ sw;
      *(bf16x4*)(Pw + wbyte) = p4;
    }
    rs += __shfl_xor(rs, 16, 64);
    rs += __shfl_xor(rs, 32, 64);
    l += rs;
#pragma unroll
    for (int s = 0; s < 2; s++) {
      int rbyte = (q * 128 + s * 64 + hi * 16) ^ sw;
      bf16x8 pa = *(const bf16x8*)(Pw + rbyte);
#pragma unroll
      for (int dt = 0; dt < 4; dt++) {
        const char* vb_ = (const char*)&Vs[cur][(dt * 16 + q) * 64];
        bf16x8 vf = *(const bf16x8*)(vb_ + ((s * 64 + hi * 16) ^ sw));
        oacc[dt] = mfma16(pa, vf, oacc[dt]);
      }
    }
    __syncthreads();  // drains next-tile DMA; all reads of buf[cur] done
    cur ^= 1;
  }

#pragma unroll
  for (int r = 0; r < 4; r++) {
    float li = 1.0f / __shfl(l, hi * 4 + r, 64);
    int row = qt * 64 + w * 16 + hi * 4 + r;
#pragma unroll
    for (int dt = 0; dt < 4; dt++) {
      Y[((size_t)nb * 1024 + row) * 768 + h * 64 + dt * 16 + q] = (bf16)(oacc[dt][r] * li);
    }
  }
}

// ---------------- LayerNorm fused with split-K reduce (1 wave per row) ----------------
// u = p0 + p1 + bias + res; then LN(u) -> of (fp32), ob (bf16, optional)
__global__ __launch_bounds__(256) void k_ln_red(const float* __restrict__ p,
                                                const float* __restrict__ bias,
                                                const float* __restrict__ res,
                                                const float* __restrict__ gam,
                                                const float* __restrict__ bet,
                                                float* __restrict__ of, bf16* __restrict__ ob,
                                                int nrows) {
  int row = blockIdx.x * 4 + (threadIdx.x >> 6);
  int lane = threadIdx.x & 63;
  if (row >= nrows) return;
  const float* p0 = p + (size_t)row * 768;
  const float* p1 = p0 + (size_t)TOK * 768;
  const float* rr = res + (size_t)row * 768;
  float v[12];
  float s = 0.f;
#pragma unroll
  for (int e = 0; e < 12; e++) {
    int c = e * 64 + lane;
    v[e] = p0[c] + p1[c] + bias[c] + rr[c];
    s += v[e];
  }
#pragma unroll
  for (int off = 32; off; off >>= 1) s += __shfl_xor(s, off, 64);
  float mean = s * (1.0f / 768.0f);
  float qv = 0.f;
#pragma unroll
  for (int e = 0; e < 12; e++) { float d = v[e] - mean; qv += d * d; }
#pragma unroll
  for (int off = 32; off; off >>= 1) qv += __shfl_xor(qv, off, 64);
  float rstd = rsqrtf(qv * (1.0f / 768.0f) + 1e-10f);
#pragma unroll
  for (int e = 0; e < 12; e++) {
    int c = e * 64 + lane;
    float o = gam[c] * (v[e] - mean) * rstd + bet[c];
    if (of) of[(size_t)row * 768 + c] = o;
    if (ob) ob[(size_t)row * 768 + c] = (bf16)o;
  }
}

// ---------------- launch ----------------
extern "C" void kernel_launch(void* const* d_in, const int* in_sizes, int n_in,
                              void* d_out, int out_size, void* d_ws, size_t ws_size,
                              hipStream_t stream) {
  const float* x   = (const float*)d_in[0];
  const float* Wq  = (const float*)d_in[1];
  const float* bq  = (const float*)d_in[2];
  const float* Wk  = (const float*)d_in[3];
  const float* bk  = (const float*)d_in[4];
  const float* Wv  = (const float*)d_in[5];
  const float* bv  = (const float*)d_in[6];
  const float* Wo  = (const float*)d_in[7];
  const float* bo  = (const float*)d_in[8];
  const float* g1  = (const float*)d_in[9];
  const float* be1 = (const float*)d_in[10];
  const float* g2  = (const float*)d_in[11];
  const float* be2 = (const float*)d_in[12];
  const float* W1  = (const float*)d_in[13];
  const float* bf1 = (const float*)d_in[14];
  const float* W2  = (const float*)d_in[15];
  const float* bf2 = (const float*)d_in[16];
  float* dout = (float*)d_out;  // fp32 output

  char* p = (char*)d_ws;
  auto alloc = [&](size_t bytes) -> char* {
    char* r = p;
    p += (bytes + 255) & ~(size_t)255;
    return r;
  };
  bf16* xb      = (bf16*)alloc((size_t)TOK * MDIM * 2);
  bf16* wqkv_t  = (bf16*)alloc((size_t)2304 * 768 * 2);
  bf16* wo_t    = (bf16*)alloc((size_t)768 * 768 * 2);
  bf16* w1_t    = (bf16*)alloc((size_t)FFD * 768 * 2);
  bf16* w2_t    = (bf16*)alloc((size_t)768 * FFD * 2);
  float* biasq  = (float*)alloc(2304 * 4);
  bf16* qb      = (bf16*)alloc((size_t)HH * TOK * 64 * 2);
  bf16* kb      = (bf16*)alloc((size_t)HH * TOK * 64 * 2);
  bf16* vb      = (bf16*)alloc((size_t)HH * TOK * 64 * 2);  // transposed [h,n][d][tok]
  bf16* yb      = (bf16*)alloc((size_t)TOK * MDIM * 2);
  float* o1f    = (float*)alloc((size_t)TOK * MDIM * 4);
  bf16* o1b     = (bf16*)alloc((size_t)TOK * MDIM * 2);
  bf16* ff1     = (bf16*)alloc((size_t)TOK * FFD * 2);
  float* part   = (float*)alloc((size_t)2 * TOK * MDIM * 4);  // split-K partials

  k_cast_x<<<TOK * MDIM / 4 / 256, 256, 0, stream>>>((const float4*)x, (bf16x4*)xb,
                                                     TOK * MDIM / 4);
  k_build_wqkv<<<dim3(12, 12, 3), 256, 0, stream>>>(Wq, Wk, Wv, wqkv_t);
  k_transpose<<<dim3(12, 12), 256, 0, stream>>>(Wo, wo_t, 768, 768);
  k_transpose<<<dim3(48, 12), 256, 0, stream>>>(W1, w1_t, 768, FFD);
  k_transpose<<<dim3(12, 48), 256, 0, stream>>>(W2, w2_t, FFD, 768);
  k_bias_qkv<<<9, 256, 0, stream>>>(bq, bk, bv, biasq);

  k_gemm<0><<<dim3(2304 / 64, TOK / 128), 256, 0, stream>>>(
      xb, wqkv_t, biasq, nullptr, nullptr, nullptr, qb, kb, vb, TOK, 2304, 768);
  k_attn<<<768, 256, 0, stream>>>(qb, kb, vb, yb);
  // out-proj: split-K, reduce fused into LN1
  k_gemm_sk<<<dim3(768 / 64, TOK / 128, 2), 256, 0, stream>>>(yb, wo_t, part, 768, 768);
  k_ln_red<<<TOK / 4, 256, 0, stream>>>(part, bo, x, g1, be1, o1f, o1b, TOK);
  // FF1 (N=3072: 48x32 = 1536 blocks = 6/CU)
  k_gemm<2><<<dim3(FFD / 64, TOK / 128), 256, 0, stream>>>(
      o1b, w1_t, bf1, nullptr, nullptr, ff1, nullptr, nullptr, nullptr, TOK, FFD, 768);
  // FF2: split-K, reduce fused into LN2
  k_gemm_sk<<<dim3(768 / 64, TOK / 128, 2), 256, 0, stream>>>(ff1, w2_t, part, 768, FFD);
  k_ln_red<<<TOK / 4, 256, 0, stream>>>(part, bf2, o1f, g2, be2, dout, nullptr, TOK);
}

// Round 13
// 255.662 us; speedup vs baseline: 1.0606x; 1.0606x over previous
//
#include <hip/hip_runtime.h>
#include <hip/hip_bf16.h>
#include <stdint.h>

// EncoderBlock: x(4,1024,768) -> MHA(12 heads, D=64) -> +res, LN -> FFN(3072,ReLU) -> +res, LN
// Output FP32. Internal compute bf16 MFMA with fp32 accumulation.

typedef __bf16 bf16;
typedef __attribute__((ext_vector_type(4))) __bf16 bf16x4;
typedef __attribute__((ext_vector_type(8))) __bf16 bf16x8;
typedef __attribute__((ext_vector_type(4))) float f32x4;

#define TOK 4096
#define MDIM 768
#define HH 12
#define FFD 3072

static __device__ __forceinline__ void gload_lds16(const bf16* g, bf16* l) {
  __builtin_amdgcn_global_load_lds(
      (const __attribute__((address_space(1))) unsigned int*)g,
      (__attribute__((address_space(3))) unsigned int*)l, 16, 0, 0);
}

static __device__ __forceinline__ f32x4 mfma16(bf16x8 a, bf16x8 b, f32x4 c) {
  return __builtin_amdgcn_mfma_f32_16x16x32_bf16(a, b, c, 0, 0, 0);
}

// ---------------- consolidated prep kernel ----------------
// One dispatch covering all mutually-independent prep work (was 6 kernels):
//   [0,1536)        cast x fp32 -> bf16 (8 elems/thread)
//   [1536,1968)     build Wqkv^T (432 = 12 mt x 12 h x 3 s), Wq scaled 1/8
//   [1968,2112)     transpose Wo   (768x768)   -> wo_t
//   [2112,2688)     transpose W1   (768x3072)  -> w1_t
//   [2688,3264)     transpose W2   (3072x768)  -> w2_t
//   [3264,3273)     bias concat (bq*0.125 | bk | bv)
// Branch is block-uniform, so __syncthreads inside tile bodies is legal.
__global__ __launch_bounds__(256) void k_prep(
    const float* __restrict__ x, bf16* __restrict__ xb,
    const float* __restrict__ Wq, const float* __restrict__ Wk,
    const float* __restrict__ Wv, bf16* __restrict__ wqkv_t,
    const float* __restrict__ Wo, bf16* __restrict__ wo_t,
    const float* __restrict__ W1, bf16* __restrict__ w1_t,
    const float* __restrict__ W2, bf16* __restrict__ w2_t,
    const float* __restrict__ bq, const float* __restrict__ bk,
    const float* __restrict__ bv, float* __restrict__ biasq) {
  __shared__ bf16 t[64][65];
  int b = blockIdx.x;
  int tid = threadIdx.x;

  if (b < 1536) {  // cast x
    size_t i = ((size_t)b * 256 + tid) * 8;
    float4 v0 = *(const float4*)(x + i);
    float4 v1 = *(const float4*)(x + i + 4);
    bf16x4 o0 = {(bf16)v0.x, (bf16)v0.y, (bf16)v0.z, (bf16)v0.w};
    bf16x4 o1 = {(bf16)v1.x, (bf16)v1.y, (bf16)v1.z, (bf16)v1.w};
    *(bf16x4*)(xb + i) = o0;
    *(bf16x4*)(xb + i + 4) = o1;
    return;
  }
  b -= 1536;
  if (b < 432) {  // build wqkv_t
    int mt = b % 12, h = (b / 12) % 12, s = b / 144;
    const float* src = (s == 0 ? Wq : s == 1 ? Wk : Wv) + (size_t)h * 768 * 64;
    float scale = (s == 0) ? 0.125f : 1.0f;
#pragma unroll
    for (int rep = 0; rep < 16; rep++) {
      int lin = rep * 256 + tid;
      int m = lin >> 6, d = lin & 63;
      t[m][d] = (bf16)(src[(size_t)(mt * 64 + m) * 64 + d] * scale);
    }
    __syncthreads();
#pragma unroll
    for (int rep = 0; rep < 16; rep++) {
      int lin = rep * 256 + tid;
      int d = lin >> 6, m = lin & 63;
      wqkv_t[(size_t)(s * 768 + h * 64 + d) * 768 + mt * 64 + m] = t[m][d];
    }
    return;
  }
  b -= 432;
  {
    const float* src;
    bf16* dst;
    int R, C, ct, rt;
    if (b < 144) { src = Wo; dst = wo_t; R = 768; C = 768; ct = b % 12; rt = b / 12; }
    else if (b < 144 + 576) {
      int b2 = b - 144;
      src = W1; dst = w1_t; R = 768; C = 3072; ct = b2 % 48; rt = b2 / 48;
    } else if (b < 144 + 1152) {
      int b2 = b - 720;
      src = W2; dst = w2_t; R = 3072; C = 768; ct = b2 % 12; rt = b2 / 12;
    } else {  // bias concat (9 blocks)
      int i = (b - 1296) * 256 + tid;
      if (i < 768) biasq[i] = bq[i] * 0.125f;
      else if (i < 1536) biasq[i] = bk[i - 768];
      else if (i < 2304) biasq[i] = bv[i - 1536];
      return;
    }
#pragma unroll
    for (int rep = 0; rep < 16; rep++) {
      int lin = rep * 256 + tid;
      int r = lin >> 6, c = lin & 63;
      t[r][c] = (bf16)src[(size_t)(rt * 64 + r) * C + ct * 64 + c];
    }
    __syncthreads();
#pragma unroll
    for (int rep = 0; rep < 16; rep++) {
      int lin = rep * 256 + tid;
      int c = lin >> 6, r = lin & 63;
      dst[(size_t)(ct * 64 + c) * R + rt * 64 + r] = t[r][c];
    }
  }
}

// ---------------- GEMM (128x128 tile, BK=64, single-buffer, T2-swizzled, T1 XCD-swizzle)
// A (Mr,K) bf16 row-major; Bt (Nc,K) bf16 row-major (= B transposed).
// XCD swizzle: each XCD owns a contiguous bx-fastest chunk of the logical grid ->
// row-panels of A are fetched once per XCD, B panels stay L2-resident.
// LDS swizzle (rule #21): dest linear, global SOURCE slot pre-swizzled, reads same XOR.
// EPI 0: QKV: Q/K -> [h][n][tok][d] bf16 (+bias); V -> transposed [h][n][d][tok] (+bias)
// EPI 2: outb bf16 = relu(acc + bias[col])
template <int EPI>
__global__ __launch_bounds__(256) void k_gemm(const bf16* __restrict__ A,
                                              const bf16* __restrict__ Bt,
                                              const float* __restrict__ bias,
                                              bf16* __restrict__ outb,
                                              bf16* __restrict__ q, bf16* __restrict__ kk,
                                              bf16* __restrict__ v,
                                              int Mr, int Nc, int K) {
  __shared__ bf16 As[128 * 64];
  __shared__ bf16 Bs[128 * 64];
  int tid = threadIdx.x, wave = tid >> 6, lane = tid & 63;
  int q_ = lane & 15, hi = lane >> 4;
  // T1: XCD-aware remap (grid size divisible by 8)
  int gx = gridDim.x;
  int bid = blockIdx.y * gx + blockIdx.x;
  int nwg = gx * gridDim.y;
  int logical = (bid & 7) * (nwg >> 3) + (bid >> 3);
  int bx = logical % gx, by = logical / gx;
  int rb = by * 128, cb = bx * 128;
  int wr = (wave >> 1) * 64, wc = (wave & 1) * 64;
  int srow = lane >> 3, jsw = (lane & 7) ^ srow;  // pre-swizzled source slot

  f32x4 acc[4][4];
#pragma unroll
  for (int m = 0; m < 4; m++)
#pragma unroll
    for (int n = 0; n < 4; n++) acc[m][n] = f32x4{0.f, 0.f, 0.f, 0.f};

  for (int k0 = 0; k0 < K; k0 += 64) {
#pragma unroll
    for (int j = 0; j < 4; j++) {
      int row = wave * 32 + j * 8;
      const bf16* ga = A + (size_t)(rb + row + srow) * K + k0 + jsw * 8;
      gload_lds16(ga, &As[row * 64]);
      const bf16* gb = Bt + (size_t)(cb + row + srow) * K + k0 + jsw * 8;
      gload_lds16(gb, &Bs[row * 64]);
    }
    __syncthreads();
#pragma unroll
    for (int ks = 0; ks < 2; ks++) {
      bf16x8 af[4], bfr[4];
#pragma unroll
      for (int m = 0; m < 4; m++) {
        int r_ = wr + m * 16 + q_;
        af[m] = *(const bf16x8*)((const char*)&As[r_ * 64] +
                                 ((ks * 64 + hi * 16) ^ ((r_ & 7) << 4)));
      }
#pragma unroll
      for (int n = 0; n < 4; n++) {
        int r_ = wc + n * 16 + q_;
        bfr[n] = *(const bf16x8*)((const char*)&Bs[r_ * 64] +
                                  ((ks * 64 + hi * 16) ^ ((r_ & 7) << 4)));
      }
#pragma unroll
      for (int m = 0; m < 4; m++)
#pragma unroll
        for (int n = 0; n < 4; n++) acc[m][n] = mfma16(af[m], bfr[n], acc[m][n]);
    }
    __syncthreads();
  }

#pragma unroll
  for (int m = 0; m < 4; m++) {
#pragma unroll
    for (int n = 0; n < 4; n++) {
      int col = cb + wc + n * 16 + q_;
      if (EPI == 0) {
        int sec = col / 768;
        int cm = col - sec * 768;
        int h = cm >> 6, d = cm & 63;
        float b = bias[col];
        if (sec < 2) {
          bf16* dst = (sec == 0 ? q : kk);
#pragma unroll
          for (int r = 0; r < 4; r++) {
            int row = rb + wr + m * 16 + hi * 4 + r;
            float val = acc[m][n][r] + b;
            dst[(((size_t)(h * 4 + (row >> 10))) * 1024 + (row & 1023)) * 64 + d] = (bf16)val;
          }
        } else {
          // V transposed: [h*4+nb][d][token], 4 consecutive tokens -> 8B packed store
          int t0 = rb + wr + m * 16 + hi * 4;
          int nb2 = t0 >> 10, tk = t0 & 1023;
          bf16x4 pk;
#pragma unroll
          for (int r = 0; r < 4; r++) pk[r] = (bf16)(acc[m][n][r] + b);
          *(bf16x4*)&v[(((size_t)(h * 4 + nb2)) * 64 + d) * 1024 + tk] = pk;
        }
      } else {
#pragma unroll
        for (int r = 0; r < 4; r++) {
          int row = rb + wr + m * 16 + hi * 4 + r;
          float t = acc[m][n][r] + bias[col];
          outb[(size_t)row * Nc + col] = (bf16)fmaxf(t, 0.f);
        }
      }
    }
  }
}

// ---------------- split-K GEMM (BM=128, BN=64, BK=64, 2 K-slices, swizzled, T1) --------
// For the N=768 GEMMs (out-proj, FF2). Grid (Nc/64, Mr/128, 2) = 768 blocks = 3/CU.
// Writes raw fp32 partials (reduced in LN).
__global__ __launch_bounds__(256) void k_gemm_sk(const bf16* __restrict__ A,
                                                 const bf16* __restrict__ Bt,
                                                 float* __restrict__ part,
                                                 int Nc, int K) {
  __shared__ bf16 As[128 * 64];
  __shared__ bf16 Bs[64 * 64];
  int tid = threadIdx.x, wave = tid >> 6, lane = tid & 63;
  int q = lane & 15, hi = lane >> 4;
  // T1: XCD-aware remap over the flattened 3-D grid (bx fastest)
  int gx = gridDim.x, gy = gridDim.y;
  int flat = (blockIdx.z * gy + blockIdx.y) * gx + blockIdx.x;
  int nwg = gx * gy * gridDim.z;
  int logical = (flat & 7) * (nwg >> 3) + (flat >> 3);
  int bx = logical % gx;
  int tmp = logical / gx;
  int by = tmp % gy, kz = tmp / gy;
  int rb = by * 128, cb = bx * 64;
  int wr = (wave >> 1) * 64, wc = (wave & 1) * 32;
  int ksz = K >> 1;
  int srow = lane >> 3, jsw = (lane & 7) ^ srow;  // pre-swizzled source slot (rule #21)

  f32x4 acc[4][2];
#pragma unroll
  for (int m = 0; m < 4; m++)
#pragma unroll
    for (int n = 0; n < 2; n++) acc[m][n] = f32x4{0.f, 0.f, 0.f, 0.f};

  for (int k0 = kz * ksz; k0 < kz * ksz + ksz; k0 += 64) {
#pragma unroll
    for (int j = 0; j < 4; j++) {
      int row = wave * 32 + j * 8;
      const bf16* ga = A + (size_t)(rb + row + srow) * K + k0 + jsw * 8;
      gload_lds16(ga, &As[row * 64]);
    }
#pragma unroll
    for (int j = 0; j < 2; j++) {
      int row = wave * 16 + j * 8;
      const bf16* gb = Bt + (size_t)(cb + row + srow) * K + k0 + jsw * 8;
      gload_lds16(gb, &Bs[row * 64]);
    }
    __syncthreads();
#pragma unroll
    for (int ks = 0; ks < 2; ks++) {
      bf16x8 af[4], bfr[2];
#pragma unroll
      for (int m = 0; m < 4; m++) {
        int r_ = wr + m * 16 + q;
        af[m] = *(const bf16x8*)((const char*)&As[r_ * 64] +
                                 ((ks * 64 + hi * 16) ^ ((r_ & 7) << 4)));
      }
#pragma unroll
      for (int n = 0; n < 2; n++) {
        int r_ = wc + n * 16 + q;
        bfr[n] = *(const bf16x8*)((const char*)&Bs[r_ * 64] +
                                  ((ks * 64 + hi * 16) ^ ((r_ & 7) << 4)));
      }
#pragma unroll
      for (int m = 0; m < 4; m++)
#pragma unroll
        for (int n = 0; n < 2; n++) acc[m][n] = mfma16(af[m], bfr[n], acc[m][n]);
    }
    __syncthreads();
  }

  float* dst = part + (size_t)kz * TOK * Nc;
#pragma unroll
  for (int m = 0; m < 4; m++)
#pragma unroll
    for (int n = 0; n < 2; n++) {
      int col = cb + wc + n * 16 + q;
#pragma unroll
      for (int r = 0; r < 4; r++) {
        int row = rb + wr + m * 16 + hi * 4 + r;
        dst[(size_t)row * Nc + col] = acc[m][n][r];
      }
    }
}

// ---------------- fused flash attention (LDS-DMA double-buffered, swapped QK^T) ----------------
// 1-D grid of 768 blocks, XCD-decoded so all 16 q-tiles of one (h,n) share an XCD.
// Q,K: [h*4+nb][1024][64] bf16 (Q pre-scaled by 1/8). Vt: [h*4+nb][64][1024] bf16.
// Y out: [nb*1024+tok][h*64+d] bf16.
__global__ __launch_bounds__(256) void k_attn(const bf16* __restrict__ Q,
                                              const bf16* __restrict__ Kb,
                                              const bf16* __restrict__ Vt,
                                              bf16* __restrict__ Y) {
  __shared__ bf16 Ks[2][64 * 64];
  __shared__ bf16 Vs[2][64 * 64];
  __shared__ bf16 Pl[4][1024];  // per-wave 16x64 P^T tile, XOR-swizzled rows (2KB/wave)
  int L = blockIdx.x;
  int grp = L >> 3;
  int pair = ((grp >> 4) << 3) | (L & 7);  // h*4+nb; same-pair blocks share XCD
  int qt = grp & 15;
  int h = pair >> 2, nb = pair & 3;
  int tid = threadIdx.x, w = tid >> 6, lane = tid & 63;
  int q = lane & 15, hi = lane >> 4;
  size_t hn = (size_t)pair * 1024;

  int srow = lane >> 3;
  int jsw = (lane & 7) ^ srow;
  const bf16* kg0 = Kb + hn * 64;
  const bf16* vg0 = Vt + (size_t)pair * 64 * 1024;

  auto stage = [&](int kt, int buf) {
#pragma unroll
    for (int c2 = 0; c2 < 2; c2++) {
      int c = w * 2 + c2;  // chunk 0..7 (8 rows each)
      const bf16* gk = kg0 + (size_t)(kt * 64 + c * 8 + srow) * 64 + jsw * 8;
      gload_lds16(gk, &Ks[buf][c * 8 * 64]);
      const bf16* gv = vg0 + (size_t)(c * 8 + srow) * 1024 + kt * 64 + jsw * 8;
      gload_lds16(gv, &Vs[buf][c * 8 * 64]);
    }
  };

  stage(0, 0);

  const bf16* qptr = Q + (hn + qt * 64 + w * 16 + q) * 64 + hi * 8;
  bf16x8 qf0 = *(const bf16x8*)qptr;
  bf16x8 qf1 = *(const bf16x8*)(qptr + 32);

  float m = -1e30f, l = 0.f;
  f32x4 oacc[4];
#pragma unroll
  for (int dt = 0; dt < 4; dt++) oacc[dt] = f32x4{0.f, 0.f, 0.f, 0.f};
  char* Pw = (char*)&Pl[w][0];
  int sw = (q & 7) << 4;  // read-side row XOR (bytes)

  __syncthreads();  // drains stage(0) DMA + Q loads

  int cur = 0;
#pragma unroll 1
  for (int kt = 0; kt < 16; kt++) {
    if (kt < 15) stage(kt + 1, cur ^ 1);  // DMA for next tile, overlaps this iter
    f32x4 sa[4];
#pragma unroll
    for (int ct = 0; ct < 4; ct++) {
      const char* kb_ = (const char*)&Ks[cur][(ct * 16 + q) * 64];
      bf16x8 kf0 = *(const bf16x8*)(kb_ + ((hi * 16) ^ sw));
      bf16x8 kf1 = *(const bf16x8*)(kb_ + ((64 + hi * 16) ^ sw));
      f32x4 z = {0.f, 0.f, 0.f, 0.f};
      z = mfma16(kf0, qf0, z);
      sa[ct] = mfma16(kf1, qf1, z);
    }
    float mx = sa[0][0];
#pragma unroll
    for (int ct = 0; ct < 4; ct++)
#pragma unroll
      for (int r = 0; r < 4; r++) mx = fmaxf(mx, sa[ct][r]);
    mx = fmaxf(mx, __shfl_xor(mx, 16, 64));
    mx = fmaxf(mx, __shfl_xor(mx, 32, 64));
    if (!__all(mx <= m)) {
      float mn = fmaxf(m, mx);
      float alpha = __expf(m - mn);
      m = mn;
      l *= alpha;
#pragma unroll
      for (int r = 0; r < 4; r++) {
        float ar = __shfl(alpha, hi * 4 + r, 64);
#pragma unroll
        for (int dt = 0; dt < 4; dt++) oacc[dt][r] *= ar;
      }
    }
    float rs = 0.f;
#pragma unroll
    for (int ct = 0; ct < 4; ct++) {
      bf16x4 p4;
#pragma unroll
      for (int r = 0; r < 4; r++) {
        float p = __expf(sa[ct][r] - m);
        rs += p;
        p4[r] = (bf16)p;
      }
      int wbyte = (q * 128 + ct * 32 + hi * 8) ^ sw;
      *(bf16x4*)(Pw + wbyte) = p4;
    }
    rs += __shfl_xor(rs, 16, 64);
    rs += __shfl_xor(rs, 32, 64);
    l += rs;
#pragma unroll
    for (int s = 0; s < 2; s++) {
      int rbyte = (q * 128 + s * 64 + hi * 16) ^ sw;
      bf16x8 pa = *(const bf16x8*)(Pw + rbyte);
#pragma unroll
      for (int dt = 0; dt < 4; dt++) {
        const char* vb_ = (const char*)&Vs[cur][(dt * 16 + q) * 64];
        bf16x8 vf = *(const bf16x8*)(vb_ + ((s * 64 + hi * 16) ^ sw));
        oacc[dt] = mfma16(pa, vf, oacc[dt]);
      }
    }
    __syncthreads();  // drains next-tile DMA; all reads of buf[cur] done
    cur ^= 1;
  }

#pragma unroll
  for (int r = 0; r < 4; r++) {
    float li = 1.0f / __shfl(l, hi * 4 + r, 64);
    int row = qt * 64 + w * 16 + hi * 4 + r;
#pragma unroll
    for (int dt = 0; dt < 4; dt++) {
      Y[((size_t)nb * 1024 + row) * 768 + h * 64 + dt * 16 + q] = (bf16)(oacc[dt][r] * li);
    }
  }
}

// ---------------- LayerNorm fused with split-K reduce (1 wave per row) ----------------
// u = p0 + p1 + bias + res; then LN(u) -> of (fp32), ob (bf16, optional)
__global__ __launch_bounds__(256) void k_ln_red(const float* __restrict__ p,
                                                const float* __restrict__ bias,
                                                const float* __restrict__ res,
                                                const float* __restrict__ gam,
                                                const float* __restrict__ bet,
                                                float* __restrict__ of, bf16* __restrict__ ob,
                                                int nrows) {
  int row = blockIdx.x * 4 + (threadIdx.x >> 6);
  int lane = threadIdx.x & 63;
  if (row >= nrows) return;
  const float* p0 = p + (size_t)row * 768;
  const float* p1 = p0 + (size_t)TOK * 768;
  const float* rr = res + (size_t)row * 768;
  float v[12];
  float s = 0.f;
#pragma unroll
  for (int e = 0; e < 12; e++) {
    int c = e * 64 + lane;
    v[e] = p0[c] + p1[c] + bias[c] + rr[c];
    s += v[e];
  }
#pragma unroll
  for (int off = 32; off; off >>= 1) s += __shfl_xor(s, off, 64);
  float mean = s * (1.0f / 768.0f);
  float qv = 0.f;
#pragma unroll
  for (int e = 0; e < 12; e++) { float d = v[e] - mean; qv += d * d; }
#pragma unroll
  for (int off = 32; off; off >>= 1) qv += __shfl_xor(qv, off, 64);
  float rstd = rsqrtf(qv * (1.0f / 768.0f) + 1e-10f);
#pragma unroll
  for (int e = 0; e < 12; e++) {
    int c = e * 64 + lane;
    float o = gam[c] * (v[e] - mean) * rstd + bet[c];
    if (of) of[(size_t)row * 768 + c] = o;
    if (ob) ob[(size_t)row * 768 + c] = (bf16)o;
  }
}

// ---------------- launch ----------------
extern "C" void kernel_launch(void* const* d_in, const int* in_sizes, int n_in,
                              void* d_out, int out_size, void* d_ws, size_t ws_size,
                              hipStream_t stream) {
  const float* x   = (const float*)d_in[0];
  const float* Wq  = (const float*)d_in[1];
  const float* bq  = (const float*)d_in[2];
  const float* Wk  = (const float*)d_in[3];
  const float* bk  = (const float*)d_in[4];
  const float* Wv  = (const float*)d_in[5];
  const float* bv  = (const float*)d_in[6];
  const float* Wo  = (const float*)d_in[7];
  const float* bo  = (const float*)d_in[8];
  const float* g1  = (const float*)d_in[9];
  const float* be1 = (const float*)d_in[10];
  const float* g2  = (const float*)d_in[11];
  const float* be2 = (const float*)d_in[12];
  const float* W1  = (const float*)d_in[13];
  const float* bf1 = (const float*)d_in[14];
  const float* W2  = (const float*)d_in[15];
  const float* bf2 = (const float*)d_in[16];
  float* dout = (float*)d_out;  // fp32 output

  char* p = (char*)d_ws;
  auto alloc = [&](size_t bytes) -> char* {
    char* r = p;
    p += (bytes + 255) & ~(size_t)255;
    return r;
  };
  bf16* xb      = (bf16*)alloc((size_t)TOK * MDIM * 2);
  bf16* wqkv_t  = (bf16*)alloc((size_t)2304 * 768 * 2);
  bf16* wo_t    = (bf16*)alloc((size_t)768 * 768 * 2);
  bf16* w1_t    = (bf16*)alloc((size_t)FFD * 768 * 2);
  bf16* w2_t    = (bf16*)alloc((size_t)768 * FFD * 2);
  float* biasq  = (float*)alloc(2304 * 4);
  bf16* qb      = (bf16*)alloc((size_t)HH * TOK * 64 * 2);
  bf16* kb      = (bf16*)alloc((size_t)HH * TOK * 64 * 2);
  bf16* vb      = (bf16*)alloc((size_t)HH * TOK * 64 * 2);  // transposed [h,n][d][tok]
  bf16* yb      = (bf16*)alloc((size_t)TOK * MDIM * 2);
  float* o1f    = (float*)alloc((size_t)TOK * MDIM * 4);
  bf16* o1b     = (bf16*)alloc((size_t)TOK * MDIM * 2);
  bf16* ff1     = (bf16*)alloc((size_t)TOK * FFD * 2);
  float* part   = (float*)alloc((size_t)2 * TOK * MDIM * 4);  // split-K partials

  // all prep in ONE dispatch (3273 blocks)
  k_prep<<<3273, 256, 0, stream>>>(x, xb, Wq, Wk, Wv, wqkv_t, Wo, wo_t, W1, w1_t,
                                   W2, w2_t, bq, bk, bv, biasq);

  k_gemm<0><<<dim3(2304 / 128, TOK / 128), 256, 0, stream>>>(
      xb, wqkv_t, biasq, nullptr, qb, kb, vb, TOK, 2304, 768);
  k_attn<<<768, 256, 0, stream>>>(qb, kb, vb, yb);
  // out-proj: split-K, reduce fused into LN1
  k_gemm_sk<<<dim3(768 / 64, TOK / 128, 2), 256, 0, stream>>>(yb, wo_t, part, 768, 768);
  k_ln_red<<<TOK / 4, 256, 0, stream>>>(part, bo, x, g1, be1, o1f, o1b, TOK);
  // FF1 (N=3072)
  k_gemm<2><<<dim3(FFD / 128, TOK / 128), 256, 0, stream>>>(
      o1b, w1_t, bf1, ff1, nullptr, nullptr, nullptr, TOK, FFD, 768);
  // FF2: split-K, reduce fused into LN2
  k_gemm_sk<<<dim3(768 / 64, TOK / 128, 2), 256, 0, stream>>>(ff1, w2_t, part, 768, FFD);
  k_ln_red<<<TOK / 4, 256, 0, stream>>>(part, bf2, o1f, g2, be2, dout, nullptr, TOK);
}